// Round 1
// baseline (388.129 us; speedup 1.0000x reference)
//
#include <hip/hip_runtime.h>
#include <hip/hip_bf16.h>
#include <math.h>

#define B_ 4
#define S_ 4096
#define DM_ 1024
#define DH_ 1024
#define M_ (B_*S_)      // 16384
#define K_ 1024
#define N1_ 3072
#define CHUNKS 64
#define CLEN 64         // S_/CHUNKS
#define NCH 4096        // B_*DH_

#define BK_ 32          // K-tile depth of the pipelined GEMM
#define NT_ (K_/BK_)    // 32 K-tiles

typedef short bf16x8 __attribute__((ext_vector_type(8)));
typedef float f32x4 __attribute__((ext_vector_type(4)));

static __device__ __forceinline__ unsigned short f2b(float f) {
  unsigned u = __float_as_uint(f);
  unsigned rounding = 0x7fffu + ((u >> 16) & 1u);
  return (unsigned short)((u + rounding) >> 16);
}
static __device__ __forceinline__ float b2f(unsigned short u) {
  return __uint_as_float(((unsigned)u) << 16);
}

// fast activations: v_exp_f32 + v_rcp_f32 (~1e-6 rel err, << bf16 rounding)
static __device__ __forceinline__ float fast_exp(float x) {
  return __builtin_amdgcn_exp2f(x * 1.4426950408889634f);
}
static __device__ __forceinline__ float fast_sigmoid(float x) {
  return __builtin_amdgcn_rcpf(1.0f + fast_exp(-x));
}
static __device__ __forceinline__ float fast_tanh(float x) {
  return 2.0f * __builtin_amdgcn_rcpf(1.0f + fast_exp(-2.0f * x)) - 1.0f;
}

// ---------- convert x (fp32 -> bf16), 4 elems/thread ----------
__global__ void cvt_x_kernel(const float* __restrict__ x, unsigned short* __restrict__ xb) {
  int i = blockIdx.x * blockDim.x + threadIdx.x;
  float4 v = reinterpret_cast<const float4*>(x)[i];
  ushort4 o;
  o.x = f2b(v.x); o.y = f2b(v.y); o.z = f2b(v.z); o.w = f2b(v.w);
  reinterpret_cast<ushort4*>(xb)[i] = o;
}

// ---------- transpose + convert: in (R x C) fp32 -> out (C x R) bf16 ----------
__global__ void transpose_cvt_kernel(const float* __restrict__ in, unsigned short* __restrict__ out,
                                     int R, int C) {
  __shared__ float tile[32][33];
  int c0 = blockIdx.x * 32, r0 = blockIdx.y * 32;
  int tx = threadIdx.x & 31, ty = threadIdx.x >> 5;  // ty 0..7
#pragma unroll
  for (int i = 0; i < 32; i += 8)
    tile[ty + i][tx] = in[(size_t)(r0 + ty + i) * C + (c0 + tx)];
  __syncthreads();
#pragma unroll
  for (int i = 0; i < 32; i += 8)
    out[(size_t)(c0 + ty + i) * R + (r0 + tx)] = f2b(tile[tx][ty + i]);
}

// ============================================================================
// GEMM: A (M x K) bf16 row-major, Bt (N x K) bf16 (B transposed).
// 256x256 tile, BK=32, 4-deep circular LDS pipeline, counted vmcnt (never 0
// in the main loop), double-barrier phases, setprio around MFMA clusters.
//
// Schedule (per K-tile t, 2 phases):
//   phase A: ds_read 4 A-frags + 4 B-frags (tile t) ; GLDS stage A(t+3)
//            ; bar ; prio1 ; 16 MFMA ; prio0 ; bar
//   phase B: ds_read 4 A-frags (B-frags reused from regs) ; GLDS stage B(t+3)
//            ; bar ; prio1 ; 16 MFMA ; prio0 ; vmcnt(8) ; bar
// Safety argument:
//  - WAR: stage of t+3 writes buf[(t+3)&3] == buf[(t-1)&3]; all waves' reads
//    of tile t-1 completed before tile t-1's final barrier (per-wave lgkm
//    waits precede its MFMAs, which precede the barrier). Stage is issued
//    after that barrier.
//  - RAW: reads of tile t+1 begin only after end-of-t vmcnt(8)+barrier.
//    vmcnt(8) leaves at most {A,B}(t+2),{A,B}(t+3) = 8 calls outstanding, so
//    every wave's contribution to tile t+1 has landed; the barrier makes that
//    globally visible. sched_barrier(0) pins next-tile ds_reads behind it.
// LDS swizzle (64B rows, 4x16B chunks): physical chunk = q ^ (r&3) ^ ((r>>2)&3)
//  -> per 16-lane ds_read_b128 phase group: 2 lanes/bank-group = free [m136].
//  Staging-side inverse is a pure lane function, so GLDS wave-uniform-base
//  constraint holds (LDS dest linear, source pre-swizzled).
// mode 1: N=3072, epilogue tanh/sigmoid -> bf16 into dst0/dst1/dst2
// mode 0: N=1024, epilogue fp32 + bias -> dstf
// ============================================================================
#define GLDS16(g, l) \
  __builtin_amdgcn_global_load_lds((const __attribute__((address_space(1))) void*)(g), \
                                   (__attribute__((address_space(3))) void*)(l), 16, 0, 0)

#define VM8 asm volatile("s_waitcnt vmcnt(8)" ::: "memory")
#define VM4 asm volatile("s_waitcnt vmcnt(4)" ::: "memory")
#define VM0 asm volatile("s_waitcnt vmcnt(0)" ::: "memory")
#define VMNONE ((void)0)

__global__ __launch_bounds__(512, 2) void gemm_act_kernel(
    const unsigned short* __restrict__ A,
    const unsigned short* __restrict__ Bt,
    const float* __restrict__ bias,
    unsigned short* __restrict__ dst0,
    unsigned short* __restrict__ dst1,
    unsigned short* __restrict__ dst2,
    float* __restrict__ dstf,
    int mode) {
  __shared__ __align__(16) unsigned short As[4][256 * BK_];  // 64 KiB
  __shared__ __align__(16) unsigned short Bs[4][256 * BK_];  // 64 KiB
  const int tid = threadIdx.x;
  const int lane = tid & 63;
  const int w = tid >> 6;            // wave 0..7
  const int wm = w & 1, wn = w >> 1; // 2x4 wave grid, each wave 128x64 of C
  const int q = lane >> 4, r16 = lane & 15;
  const int tileM = blockIdx.y * 256;
  const int tileN = blockIdx.x * 256;

  // staging: one GLDS call covers 16 rows x 64B; lane -> (row srow, chunk lane&3)
  const int srow = lane >> 2;                                   // 0..15
  const int slc = ((lane & 3) ^ ((lane >> 2) & 3) ^ ((lane >> 4) & 3)) * 8;  // src swizzle (elems)
  // read-side physical chunk offset (elems); row-base bits vanish mod 16
  const int ach = (q ^ (r16 & 3) ^ ((r16 >> 2) & 3)) * 8;

  f32x4 zero = {0.f, 0.f, 0.f, 0.f};
  f32x4 acc[8][4];
#pragma unroll
  for (int i = 0; i < 8; ++i)
#pragma unroll
    for (int j = 0; j < 4; ++j) acc[i][j] = zero;

#define STAGE_A(tt) do { \
    _Pragma("unroll") \
    for (int c_ = 0; c_ < 2; ++c_) { \
      const int rb_ = (w * 2 + c_) * 16; \
      GLDS16(A + (size_t)(tileM + rb_ + srow) * K_ + (tt) * BK_ + slc, \
             &As[(tt) & 3][rb_ * BK_]); \
    } } while (0)
#define STAGE_B(tt) do { \
    _Pragma("unroll") \
    for (int c_ = 0; c_ < 2; ++c_) { \
      const int rb_ = (w * 2 + c_) * 16; \
      GLDS16(Bt + (size_t)(tileN + rb_ + srow) * K_ + (tt) * BK_ + slc, \
             &Bs[(tt) & 3][rb_ * BK_]); \
    } } while (0)

#define TILE(t, STG, VMX) do { \
    const int buf_ = (t) & 3; \
    bf16x8 af0[4], af1[4], bfr[4]; \
    _Pragma("unroll") \
    for (int i = 0; i < 4; ++i) \
      af0[i] = *(const bf16x8*)&As[buf_][(wm * 128 + i * 16 + r16) * BK_ + ach]; \
    _Pragma("unroll") \
    for (int j = 0; j < 4; ++j) \
      bfr[j] = *(const bf16x8*)&Bs[buf_][(wn * 64 + j * 16 + r16) * BK_ + ach]; \
    if (STG) STAGE_A((t) + 3); \
    __builtin_amdgcn_s_barrier(); \
    __builtin_amdgcn_s_setprio(1); \
    _Pragma("unroll") \
    for (int i = 0; i < 4; ++i) \
      _Pragma("unroll") \
      for (int j = 0; j < 4; ++j) \
        acc[i][j] = __builtin_amdgcn_mfma_f32_16x16x32_bf16(af0[i], bfr[j], acc[i][j], 0, 0, 0); \
    __builtin_amdgcn_s_setprio(0); \
    __builtin_amdgcn_s_barrier(); \
    _Pragma("unroll") \
    for (int i = 0; i < 4; ++i) \
      af1[i] = *(const bf16x8*)&As[buf_][(wm * 128 + 64 + i * 16 + r16) * BK_ + ach]; \
    if (STG) STAGE_B((t) + 3); \
    __builtin_amdgcn_s_barrier(); \
    __builtin_amdgcn_s_setprio(1); \
    _Pragma("unroll") \
    for (int i = 0; i < 4; ++i) \
      _Pragma("unroll") \
      for (int j = 0; j < 4; ++j) \
        acc[4 + i][j] = __builtin_amdgcn_mfma_f32_16x16x32_bf16(af1[i], bfr[j], acc[4 + i][j], 0, 0, 0); \
    __builtin_amdgcn_s_setprio(0); \
    VMX; \
    __builtin_amdgcn_s_barrier(); \
    __builtin_amdgcn_sched_barrier(0); \
  } while (0)

  // prologue: stage tiles 0,1,2 (12 calls/thread); vmcnt(8) -> tile 0 resident
  STAGE_A(0); STAGE_B(0);
  STAGE_A(1); STAGE_B(1);
  STAGE_A(2); STAGE_B(2);
  VM8;
  __builtin_amdgcn_s_barrier();
  __builtin_amdgcn_sched_barrier(0);

#pragma unroll 1
  for (int t = 0; t < NT_ - 3; ++t) {  // t = 0..28, stages tiles 3..31
    TILE(t, 1, VM8);
  }
  TILE(NT_ - 3, 0, VM4);
  TILE(NT_ - 2, 0, VM0);
  TILE(NT_ - 1, 0, VMNONE);

  // epilogue: C/D layout col = lane&15, row = (lane>>4)*4 + reg  [m89]
  if (mode == 1) {
    int cls = tileN >> 10;  // 0: tanh->dst0, 1: sigmoid->dst1, 2: sigmoid->dst2
    unsigned short* dst = (cls == 0) ? dst0 : ((cls == 1) ? dst1 : dst2);
    int ncol0 = tileN & 1023;
#pragma unroll
    for (int i = 0; i < 8; ++i) {
#pragma unroll
      for (int j = 0; j < 4; ++j) {
        int nl = wn * 64 + j * 16 + r16;
        float bb = bias[tileN + nl];
#pragma unroll
        for (int r = 0; r < 4; ++r) {
          int m = tileM + wm * 128 + i * 16 + q * 4 + r;
          float u = acc[i][j][r] + bb;
          float v = (cls == 0) ? fast_tanh(u) : fast_sigmoid(u);
          dst[(size_t)m * 1024 + (ncol0 + nl)] = f2b(v);
        }
      }
    }
  } else {
#pragma unroll
    for (int i = 0; i < 8; ++i) {
#pragma unroll
      for (int j = 0; j < 4; ++j) {
        int nl = wn * 64 + j * 16 + r16;
        float bb = bias[tileN + nl];
#pragma unroll
        for (int r = 0; r < 4; ++r) {
          int m = tileM + wm * 128 + i * 16 + q * 4 + r;
          dstf[(size_t)m * 1024 + tileN + nl] = acc[i][j][r] + bb;
        }
      }
    }
  }
#undef TILE
#undef STAGE_A
#undef STAGE_B
}

// ---------- scan pass A: per (b, chunk, 256-channel group) compute (prodF, localScan) ----------
__global__ void scanA_kernel(const unsigned short* __restrict__ a0,
                             const unsigned short* __restrict__ a1,
                             float* __restrict__ cF, float* __restrict__ cS) {
  int bid = blockIdx.x;
  int dhb = bid & 3;
  int j = (bid >> 2) & 63;
  int b = bid >> 8;
  int dh = dhb * 256 + threadIdx.x;
  size_t base = ((size_t)b * S_ + (size_t)j * CLEN) * DH_ + dh;
  float F = 1.f, Sv = 0.f;
#pragma unroll 4
  for (int t = 0; t < CLEN; ++t) {
    float inp = b2f(a0[base + (size_t)t * DH_]);
    float ig = b2f(a1[base + (size_t)t * DH_]);
    float f = 1.f - ig;
    F *= f;
    Sv = f * Sv + inp * ig;
  }
  int ch = b * DH_ + dh;
  cF[j * NCH + ch] = F;
  cS[j * NCH + ch] = Sv;
}

// ---------- scan pass B: sequential combine over chunks; emits carry-in per chunk + h_last ----------
__global__ void scanB_kernel(const float* __restrict__ cF, const float* __restrict__ cS,
                             float* __restrict__ cIn, float* __restrict__ hlast) {
  int ch = blockIdx.x * blockDim.x + threadIdx.x;  // 0..4095
  float h = 0.f;
#pragma unroll 4
  for (int j = 0; j < CHUNKS; ++j) {
    cIn[j * NCH + ch] = h;
    h = cF[j * NCH + ch] * h + cS[j * NCH + ch];
  }
  hlast[ch] = h;  // output 0: h[:, -1, :]
}

// ---------- scan pass C: recompute with carry-in, y = tanh(h)*og -> bf16 ----------
__global__ void scanC_kernel(const unsigned short* __restrict__ a0,
                             const unsigned short* __restrict__ a1,
                             const unsigned short* __restrict__ a2,
                             const float* __restrict__ cIn,
                             unsigned short* __restrict__ yb) {
  int bid = blockIdx.x;
  int dhb = bid & 3;
  int j = (bid >> 2) & 63;
  int b = bid >> 8;
  int dh = dhb * 256 + threadIdx.x;
  int ch = b * DH_ + dh;
  size_t base = ((size_t)b * S_ + (size_t)j * CLEN) * DH_ + dh;
  float h = cIn[j * NCH + ch];
#pragma unroll 4
  for (int t = 0; t < CLEN; ++t) {
    size_t idx = base + (size_t)t * DH_;
    float inp = b2f(a0[idx]);
    float ig = b2f(a1[idx]);
    float og = b2f(a2[idx]);
    float f = 1.f - ig;
    h = f * h + inp * ig;
    yb[idx] = f2b(fast_tanh(h) * og);
  }
}

extern "C" void kernel_launch(void* const* d_in, const int* in_sizes, int n_in,
                              void* d_out, int out_size, void* d_ws, size_t ws_size,
                              hipStream_t stream) {
  const float* x = (const float*)d_in[0];
  const float* Wp = (const float*)d_in[1];
  const float* bp = (const float*)d_in[2];
  const float* Wo = (const float*)d_in[3];
  const float* bo = (const float*)d_in[4];
  float* out = (float*)d_out;

  char* w = (char*)d_ws;
  unsigned short* xb = (unsigned short*)w;  w += (size_t)M_ * K_ * 2;       // 32 MiB
  unsigned short* wpt = (unsigned short*)w; w += (size_t)N1_ * K_ * 2;      // 6 MiB
  unsigned short* wot = (unsigned short*)w; w += (size_t)DM_ * K_ * 2;      // 2 MiB
  unsigned short* a0 = (unsigned short*)w;  w += (size_t)M_ * DH_ * 2;      // 32 MiB
  unsigned short* a1 = (unsigned short*)w;  w += (size_t)M_ * DH_ * 2;
  unsigned short* a2 = (unsigned short*)w;  w += (size_t)M_ * DH_ * 2;
  float* cF = (float*)w;  w += (size_t)NCH * CHUNKS * 4;                    // 1 MiB
  float* cS = (float*)w;  w += (size_t)NCH * CHUNKS * 4;
  float* cIn = (float*)w; w += (size_t)NCH * CHUNKS * 4;
  unsigned short* yb = xb;  // alias: xb dead after GEMM1

  cvt_x_kernel<<<(M_ * K_ / 4) / 256, 256, 0, stream>>>(x, xb);
  transpose_cvt_kernel<<<dim3(N1_ / 32, K_ / 32), 256, 0, stream>>>(Wp, wpt, K_, N1_);
  transpose_cvt_kernel<<<dim3(DM_ / 32, DH_ / 32), 256, 0, stream>>>(Wo, wot, DH_, DM_);

  gemm_act_kernel<<<dim3(N1_ / 256, M_ / 256), 512, 0, stream>>>(
      xb, wpt, bp, a0, a1, a2, nullptr, 1);

  scanA_kernel<<<B_ * CHUNKS * (DH_ / 256), 256, 0, stream>>>(a0, a1, cF, cS);
  scanB_kernel<<<NCH / 256, 256, 0, stream>>>(cF, cS, cIn, out);
  scanC_kernel<<<B_ * CHUNKS * (DH_ / 256), 256, 0, stream>>>(a0, a1, a2, cIn, yb);

  gemm_act_kernel<<<dim3(DM_ / 256, M_ / 256), 512, 0, stream>>>(
      yb, wot, bo, nullptr, nullptr, nullptr, out + 4096, 0);
}

// Round 2
// 351.770 us; speedup vs baseline: 1.1034x; 1.1034x over previous
//
#include <hip/hip_runtime.h>
#include <hip/hip_bf16.h>
#include <math.h>

#define B_ 4
#define S_ 4096
#define DM_ 1024
#define DH_ 1024
#define M_ (B_*S_)      // 16384
#define K_ 1024
#define N1_ 3072
#define CHUNKS 64
#define CLEN 64         // S_/CHUNKS
#define NCH 4096        // B_*DH_

#define BK_ 64          // K-tile depth (128B rows -> grouping-robust swizzle)
#define NT_ (K_/BK_)    // 16 K-tiles

typedef short bf16x8 __attribute__((ext_vector_type(8)));
typedef float f32x4 __attribute__((ext_vector_type(4)));

static __device__ __forceinline__ unsigned short f2b(float f) {
  unsigned u = __float_as_uint(f);
  unsigned rounding = 0x7fffu + ((u >> 16) & 1u);
  return (unsigned short)((u + rounding) >> 16);
}
static __device__ __forceinline__ float b2f(unsigned short u) {
  return __uint_as_float(((unsigned)u) << 16);
}

// fast activations: v_exp_f32 + v_rcp_f32 (~1e-6 rel err, << bf16 rounding)
static __device__ __forceinline__ float fast_exp(float x) {
  return __builtin_amdgcn_exp2f(x * 1.4426950408889634f);
}
static __device__ __forceinline__ float fast_sigmoid(float x) {
  return __builtin_amdgcn_rcpf(1.0f + fast_exp(-x));
}
static __device__ __forceinline__ float fast_tanh(float x) {
  return 2.0f * __builtin_amdgcn_rcpf(1.0f + fast_exp(-2.0f * x)) - 1.0f;
}

// ---------- convert x (fp32 -> bf16), 4 elems/thread ----------
__global__ void cvt_x_kernel(const float* __restrict__ x, unsigned short* __restrict__ xb) {
  int i = blockIdx.x * blockDim.x + threadIdx.x;
  float4 v = reinterpret_cast<const float4*>(x)[i];
  ushort4 o;
  o.x = f2b(v.x); o.y = f2b(v.y); o.z = f2b(v.z); o.w = f2b(v.w);
  reinterpret_cast<ushort4*>(xb)[i] = o;
}

// ---------- transpose + convert: in (R x C) fp32 -> out (C x R) bf16 ----------
__global__ void transpose_cvt_kernel(const float* __restrict__ in, unsigned short* __restrict__ out,
                                     int R, int C) {
  __shared__ float tile[32][33];
  int c0 = blockIdx.x * 32, r0 = blockIdx.y * 32;
  int tx = threadIdx.x & 31, ty = threadIdx.x >> 5;  // ty 0..7
#pragma unroll
  for (int i = 0; i < 32; i += 8)
    tile[ty + i][tx] = in[(size_t)(r0 + ty + i) * C + (c0 + tx)];
  __syncthreads();
#pragma unroll
  for (int i = 0; i < 32; i += 8)
    out[(size_t)(c0 + ty + i) * R + (r0 + tx)] = f2b(tile[tx][ty + i]);
}

// ============================================================================
// GEMM: A (M x K) bf16 row-major, Bt (N x K) bf16 (B transposed).
// 256x256 tile, BK=64, double-buffered LDS, 4 phases/K-tile (m-half x k-half),
// staggered staging + counted vmcnt (never 0 in main loop), setprio on MFMA.
//
// LDS layout (PROVEN zero-conflict from the 128^2 kernel): rows of 128B =
// 8 x 16B chunks; logical chunk c of row r stored at physical c^(r&7).
// Bank group of a chunk = chunk index (row stride 128B = full bank span), so
// conflict-freedom is independent of HW lane-phase grouping.
//   stage side: GLDS call covers 8 rows; lane l -> row base+(l>>3), phys chunk
//     l&7, global logical chunk (l&7)^(l>>3). LDS dest linear (wave-uniform
//     base + lane*16) -> GLDS constraint holds.
//   read side: chunk ((kk*4+q) ^ (r16&7)).
//
// Phase schedule per K-tile t (buf = t&1):
//  ph1 (m0,k0): ds_read af(4)+bf0(4); stage A2,A3(t+1); bar; lgkm0; 16 MFMA; bar
//  ph2 (m1,k0): ds_read af(4);        stage B2,B3(t+1); bar; lgkm0; 16 MFMA; bar
//  ph3 (m0,k1): ds_read af(4)+bf1(4);                   bar; lgkm0; 16 MFMA; bar
//  ph4 (m1,k1): ds_read af(4); bar; lgkm0; stage A0,A1,B0,B1(t+2); 16 MFMA;
//               vmcnt(4); bar
// Hazards:
//  - WAR(t+1 staging, ph1/ph2): buf[(t+1)&1] held t-1; all reads of t-1 done
//    before t-1's final barrier, which precedes these issues.
//  - WAR(t+2 staging, ph4): targets buf[t&1] (current tile!) -> issued only
//    after ph4's mid-barrier, which follows the LAST ds_reads of tile t in
//    all waves.
//  - RAW(t+1): at ph4 vmcnt(4), per-wave outstanding (issue order) are
//    {t+1: 8 calls} then {t+2: 4 calls}; vmcnt(4) retires all of t+1; the
//    following barrier publishes. Freshest waited-on load is ~2 phases old.
// mode 1: N=3072, epilogue tanh/sigmoid -> bf16 into dst0/dst1/dst2
// mode 0: N=1024, epilogue fp32 + bias -> dstf
// ============================================================================
#define GLDS16(g, l) \
  __builtin_amdgcn_global_load_lds((const __attribute__((address_space(1))) void*)(g), \
                                   (__attribute__((address_space(3))) void*)(l), 16, 0, 0)

#define VM4 asm volatile("s_waitcnt vmcnt(4)" ::: "memory")
#define VM0 asm volatile("s_waitcnt vmcnt(0)" ::: "memory")
#define VMNONE ((void)0)
#define LGKM0 do { asm volatile("s_waitcnt lgkmcnt(0)" ::: "memory"); \
                   __builtin_amdgcn_sched_barrier(0); } while (0)
#define BAR do { __builtin_amdgcn_s_barrier(); \
                 __builtin_amdgcn_sched_barrier(0); } while (0)

__global__ __launch_bounds__(512, 2) void gemm_act_kernel(
    const unsigned short* __restrict__ A,
    const unsigned short* __restrict__ Bt,
    const float* __restrict__ bias,
    unsigned short* __restrict__ dst0,
    unsigned short* __restrict__ dst1,
    unsigned short* __restrict__ dst2,
    float* __restrict__ dstf,
    int mode) {
  __shared__ __align__(16) unsigned short As[2][256 * BK_];  // 64 KiB
  __shared__ __align__(16) unsigned short Bs[2][256 * BK_];  // 64 KiB
  const int tid = threadIdx.x;
  const int lane = tid & 63;
  const int w = tid >> 6;            // wave 0..7
  const int wm = w & 1, wn = w >> 1; // 2x4 wave grid, each wave 128x64 of C
  const int q = lane >> 4, r16 = lane & 15;
  const int tileM = blockIdx.y * 256;
  const int tileN = blockIdx.x * 256;

  // staging lane mapping (proven zero-conflict layout)
  const int srow = lane >> 3;                          // 0..7
  const int schunk = ((lane & 7) ^ (lane >> 3)) * 8;   // source chunk (elems)

  f32x4 zero = {0.f, 0.f, 0.f, 0.f};
  f32x4 acc[8][4];
#pragma unroll
  for (int i = 0; i < 8; ++i)
#pragma unroll
    for (int j = 0; j < 4; ++j) acc[i][j] = zero;

#define STAGEA(tt, p) \
  GLDS16(A + (size_t)(tileM + w * 32 + (p) * 8 + srow) * K_ + (tt) * BK_ + schunk, \
         &As[(tt) & 1][(w * 32 + (p) * 8) * BK_])
#define STAGEB(tt, p) \
  GLDS16(Bt + (size_t)(tileN + w * 32 + (p) * 8 + srow) * K_ + (tt) * BK_ + schunk, \
         &Bs[(tt) & 1][(w * 32 + (p) * 8) * BK_])

#define RD_A(dst, mh, kk, buf_) \
  _Pragma("unroll") \
  for (int i = 0; i < 4; ++i) \
    dst[i] = *(const bf16x8*)&As[buf_][(wm * 128 + (mh) * 64 + i * 16 + r16) * BK_ + \
                                       ((((kk) * 4 + q) ^ (r16 & 7)) * 8)];
#define RD_B(dst, kk, buf_) \
  _Pragma("unroll") \
  for (int j = 0; j < 4; ++j) \
    dst[j] = *(const bf16x8*)&Bs[buf_][(wn * 64 + j * 16 + r16) * BK_ + \
                                       ((((kk) * 4 + q) ^ (r16 & 7)) * 8)];
#define MFMA16(ib, bfr) \
  __builtin_amdgcn_s_setprio(1); \
  _Pragma("unroll") \
  for (int i = 0; i < 4; ++i) \
    _Pragma("unroll") \
    for (int j = 0; j < 4; ++j) \
      acc[(ib) + i][j] = __builtin_amdgcn_mfma_f32_16x16x32_bf16(af[i], bfr[j], acc[(ib) + i][j], 0, 0, 0); \
  __builtin_amdgcn_s_setprio(0);

#define TILE(t, S1, S2, VMX) do { \
    const int buf_ = (t) & 1; \
    bf16x8 af[4], bf0[4], bf1[4]; \
    /* ph1: m-half 0, k-half 0 */ \
    RD_A(af, 0, 0, buf_); \
    RD_B(bf0, 0, buf_); \
    if (S1) { STAGEA((t) + 1, 2); STAGEA((t) + 1, 3); } \
    __builtin_amdgcn_s_barrier(); \
    LGKM0; \
    MFMA16(0, bf0); \
    BAR; \
    /* ph2: m-half 1, k-half 0 */ \
    RD_A(af, 1, 0, buf_); \
    if (S1) { STAGEB((t) + 1, 2); STAGEB((t) + 1, 3); } \
    __builtin_amdgcn_s_barrier(); \
    LGKM0; \
    MFMA16(4, bf0); \
    BAR; \
    /* ph3: m-half 0, k-half 1 */ \
    RD_A(af, 0, 1, buf_); \
    RD_B(bf1, 1, buf_); \
    __builtin_amdgcn_s_barrier(); \
    LGKM0; \
    MFMA16(0, bf1); \
    BAR; \
    /* ph4: m-half 1, k-half 1 */ \
    RD_A(af, 1, 1, buf_); \
    __builtin_amdgcn_s_barrier(); \
    LGKM0; \
    if (S2) { STAGEA((t) + 2, 0); STAGEA((t) + 2, 1); STAGEB((t) + 2, 0); STAGEB((t) + 2, 1); } \
    MFMA16(4, bf1); \
    VMX; \
    BAR; \
  } while (0)

  // prologue: tile0 fully (8 calls) + tile1 first half (4 calls); wait tile0
  STAGEA(0, 0); STAGEA(0, 1); STAGEA(0, 2); STAGEA(0, 3);
  STAGEB(0, 0); STAGEB(0, 1); STAGEB(0, 2); STAGEB(0, 3);
  STAGEA(1, 0); STAGEA(1, 1); STAGEB(1, 0); STAGEB(1, 1);
  VM4;
  BAR;

#pragma unroll 1
  for (int t = 0; t < NT_ - 2; ++t) {  // t = 0..13
    TILE(t, 1, 1, VM4);
  }
  TILE(NT_ - 2, 1, 0, VM0);
  TILE(NT_ - 1, 0, 0, VMNONE);

  // epilogue: C/D layout col = lane&15, row = (lane>>4)*4 + reg  [m89]
  // acc[ii][j]: rows tileM + wm*128 + (ii>>2)*64 + (ii&3)*16 + q*4 + r
  if (mode == 1) {
    int cls = tileN >> 10;  // 0: tanh->dst0, 1: sigmoid->dst1, 2: sigmoid->dst2
    unsigned short* dst = (cls == 0) ? dst0 : ((cls == 1) ? dst1 : dst2);
    int ncol0 = tileN & 1023;
#pragma unroll
    for (int ii = 0; ii < 8; ++ii) {
#pragma unroll
      for (int j = 0; j < 4; ++j) {
        int nl = wn * 64 + j * 16 + r16;
        float bb = bias[tileN + nl];
#pragma unroll
        for (int r = 0; r < 4; ++r) {
          int m = tileM + wm * 128 + (ii >> 2) * 64 + (ii & 3) * 16 + q * 4 + r;
          float u = acc[ii][j][r] + bb;
          float v = (cls == 0) ? fast_tanh(u) : fast_sigmoid(u);
          dst[(size_t)m * 1024 + (ncol0 + nl)] = f2b(v);
        }
      }
    }
  } else {
#pragma unroll
    for (int ii = 0; ii < 8; ++ii) {
#pragma unroll
      for (int j = 0; j < 4; ++j) {
        int nl = wn * 64 + j * 16 + r16;
        float bb = bias[tileN + nl];
#pragma unroll
        for (int r = 0; r < 4; ++r) {
          int m = tileM + wm * 128 + (ii >> 2) * 64 + (ii & 3) * 16 + q * 4 + r;
          dstf[(size_t)m * 1024 + tileN + nl] = acc[ii][j][r] + bb;
        }
      }
    }
  }
#undef TILE
#undef MFMA16
#undef RD_A
#undef RD_B
#undef STAGEA
#undef STAGEB
}

// ---------- scan pass A: per (b, chunk, 256-channel group) compute (prodF, localScan) ----------
__global__ void scanA_kernel(const unsigned short* __restrict__ a0,
                             const unsigned short* __restrict__ a1,
                             float* __restrict__ cF, float* __restrict__ cS) {
  int bid = blockIdx.x;
  int dhb = bid & 3;
  int j = (bid >> 2) & 63;
  int b = bid >> 8;
  int dh = dhb * 256 + threadIdx.x;
  size_t base = ((size_t)b * S_ + (size_t)j * CLEN) * DH_ + dh;
  float F = 1.f, Sv = 0.f;
#pragma unroll 4
  for (int t = 0; t < CLEN; ++t) {
    float inp = b2f(a0[base + (size_t)t * DH_]);
    float ig = b2f(a1[base + (size_t)t * DH_]);
    float f = 1.f - ig;
    F *= f;
    Sv = f * Sv + inp * ig;
  }
  int ch = b * DH_ + dh;
  cF[j * NCH + ch] = F;
  cS[j * NCH + ch] = Sv;
}

// ---------- scan pass B: sequential combine over chunks; emits carry-in per chunk + h_last ----------
__global__ void scanB_kernel(const float* __restrict__ cF, const float* __restrict__ cS,
                             float* __restrict__ cIn, float* __restrict__ hlast) {
  int ch = blockIdx.x * blockDim.x + threadIdx.x;  // 0..4095
  float h = 0.f;
#pragma unroll 4
  for (int j = 0; j < CHUNKS; ++j) {
    cIn[j * NCH + ch] = h;
    h = cF[j * NCH + ch] * h + cS[j * NCH + ch];
  }
  hlast[ch] = h;  // output 0: h[:, -1, :]
}

// ---------- scan pass C: recompute with carry-in, y = tanh(h)*og -> bf16 ----------
__global__ void scanC_kernel(const unsigned short* __restrict__ a0,
                             const unsigned short* __restrict__ a1,
                             const unsigned short* __restrict__ a2,
                             const float* __restrict__ cIn,
                             unsigned short* __restrict__ yb) {
  int bid = blockIdx.x;
  int dhb = bid & 3;
  int j = (bid >> 2) & 63;
  int b = bid >> 8;
  int dh = dhb * 256 + threadIdx.x;
  int ch = b * DH_ + dh;
  size_t base = ((size_t)b * S_ + (size_t)j * CLEN) * DH_ + dh;
  float h = cIn[j * NCH + ch];
#pragma unroll 4
  for (int t = 0; t < CLEN; ++t) {
    size_t idx = base + (size_t)t * DH_;
    float inp = b2f(a0[idx]);
    float ig = b2f(a1[idx]);
    float og = b2f(a2[idx]);
    float f = 1.f - ig;
    h = f * h + inp * ig;
    yb[idx] = f2b(fast_tanh(h) * og);
  }
}

extern "C" void kernel_launch(void* const* d_in, const int* in_sizes, int n_in,
                              void* d_out, int out_size, void* d_ws, size_t ws_size,
                              hipStream_t stream) {
  const float* x = (const float*)d_in[0];
  const float* Wp = (const float*)d_in[1];
  const float* bp = (const float*)d_in[2];
  const float* Wo = (const float*)d_in[3];
  const float* bo = (const float*)d_in[4];
  float* out = (float*)d_out;

  char* w = (char*)d_ws;
  unsigned short* xb = (unsigned short*)w;  w += (size_t)M_ * K_ * 2;       // 32 MiB
  unsigned short* wpt = (unsigned short*)w; w += (size_t)N1_ * K_ * 2;      // 6 MiB
  unsigned short* wot = (unsigned short*)w; w += (size_t)DM_ * K_ * 2;      // 2 MiB
  unsigned short* a0 = (unsigned short*)w;  w += (size_t)M_ * DH_ * 2;      // 32 MiB
  unsigned short* a1 = (unsigned short*)w;  w += (size_t)M_ * DH_ * 2;
  unsigned short* a2 = (unsigned short*)w;  w += (size_t)M_ * DH_ * 2;
  float* cF = (float*)w;  w += (size_t)NCH * CHUNKS * 4;                    // 1 MiB
  float* cS = (float*)w;  w += (size_t)NCH * CHUNKS * 4;
  float* cIn = (float*)w; w += (size_t)NCH * CHUNKS * 4;
  unsigned short* yb = xb;  // alias: xb dead after GEMM1

  cvt_x_kernel<<<(M_ * K_ / 4) / 256, 256, 0, stream>>>(x, xb);
  transpose_cvt_kernel<<<dim3(N1_ / 32, K_ / 32), 256, 0, stream>>>(Wp, wpt, K_, N1_);
  transpose_cvt_kernel<<<dim3(DM_ / 32, DH_ / 32), 256, 0, stream>>>(Wo, wot, DH_, DM_);

  gemm_act_kernel<<<dim3(N1_ / 256, M_ / 256), 512, 0, stream>>>(
      xb, wpt, bp, a0, a1, a2, nullptr, 1);

  scanA_kernel<<<B_ * CHUNKS * (DH_ / 256), 256, 0, stream>>>(a0, a1, cF, cS);
  scanB_kernel<<<NCH / 256, 256, 0, stream>>>(cF, cS, cIn, out);
  scanC_kernel<<<B_ * CHUNKS * (DH_ / 256), 256, 0, stream>>>(a0, a1, a2, cIn, yb);

  gemm_act_kernel<<<dim3(DM_ / 256, M_ / 256), 512, 0, stream>>>(
      yb, wot, bo, nullptr, nullptr, nullptr, out + 4096, 0);
}

// Round 3
// 332.787 us; speedup vs baseline: 1.1663x; 1.0570x over previous
//
#include <hip/hip_runtime.h>
#include <hip/hip_bf16.h>
#include <math.h>

#define B_ 4
#define S_ 4096
#define DM_ 1024
#define DH_ 1024
#define M_ (B_*S_)      // 16384
#define K_ 1024
#define N1_ 3072
#define CHUNKS 64
#define CLEN 64         // S_/CHUNKS
#define NCH 4096        // B_*DH_

#define BK_ 64          // K-tile depth (128B rows -> grouping-robust swizzle)
#define NT_ (K_/BK_)    // 16 K-tiles
#define TS_ (256*BK_)   // elems per tile buffer (32 KiB)

typedef short bf16x8 __attribute__((ext_vector_type(8)));
typedef float f32x4 __attribute__((ext_vector_type(4)));

static __device__ __forceinline__ unsigned short f2b(float f) {
  unsigned u = __float_as_uint(f);
  unsigned rounding = 0x7fffu + ((u >> 16) & 1u);
  return (unsigned short)((u + rounding) >> 16);
}
static __device__ __forceinline__ float b2f(unsigned short u) {
  return __uint_as_float(((unsigned)u) << 16);
}

// fast activations: v_exp_f32 + v_rcp_f32 (~1e-6 rel err, << bf16 rounding)
static __device__ __forceinline__ float fast_exp(float x) {
  return __builtin_amdgcn_exp2f(x * 1.4426950408889634f);
}
static __device__ __forceinline__ float fast_sigmoid(float x) {
  return __builtin_amdgcn_rcpf(1.0f + fast_exp(-x));
}
static __device__ __forceinline__ float fast_tanh(float x) {
  return 2.0f * __builtin_amdgcn_rcpf(1.0f + fast_exp(-2.0f * x)) - 1.0f;
}

// ---------- convert x (fp32 -> bf16), 4 elems/thread ----------
__global__ void cvt_x_kernel(const float* __restrict__ x, unsigned short* __restrict__ xb) {
  int i = blockIdx.x * blockDim.x + threadIdx.x;
  float4 v = reinterpret_cast<const float4*>(x)[i];
  ushort4 o;
  o.x = f2b(v.x); o.y = f2b(v.y); o.z = f2b(v.z); o.w = f2b(v.w);
  reinterpret_cast<ushort4*>(xb)[i] = o;
}

// ---------- transpose + convert: in (R x C) fp32 -> out (C x R) bf16 ----------
__global__ void transpose_cvt_kernel(const float* __restrict__ in, unsigned short* __restrict__ out,
                                     int R, int C) {
  __shared__ float tile[32][33];
  int c0 = blockIdx.x * 32, r0 = blockIdx.y * 32;
  int tx = threadIdx.x & 31, ty = threadIdx.x >> 5;  // ty 0..7
#pragma unroll
  for (int i = 0; i < 32; i += 8)
    tile[ty + i][tx] = in[(size_t)(r0 + ty + i) * C + (c0 + tx)];
  __syncthreads();
#pragma unroll
  for (int i = 0; i < 32; i += 8)
    out[(size_t)(c0 + ty + i) * R + (r0 + tx)] = f2b(tile[tx][ty + i]);
}

// ============================================================================
// GEMM: A (M x K) bf16 row-major, Bt (N x K) bf16 (B transposed).
// 256x256 tile, BK=64, 4 phases/K-tile, SOFTWARE-PIPELINED ds_reads:
// phase p issues ds_reads for phase p+1's MFMA; counted lgkmcnt(4/8) (never 0
// in the main loop) waits only for operands issued ONE PHASE earlier, so the
// LDS pipe streams reads of p+1 while MFMA of p executes. Counted vmcnt(2)
// once per tile publishes staging with >=2-phase HBM lead.
//
// Buffers: A 2-deep (64 KiB) + B 3-deep (96 KiB) = 160 KiB LDS (full pool).
// B needs 3 because B(t+2) staging starts at tP2 while B(t) is still read.
//
// LDS layout (proven zero-conflict, round-2 measured 0 conflicts): rows of
// 128B = 8x16B chunks; logical chunk c of row r stored at physical c^(r&7).
// Stage side: GLDS call covers 8 rows; lane l -> row base+(l>>3), source
// chunk (l&7)^(l>>3); LDS dest linear -> GLDS wave-uniform constraint holds.
// Read side: chunk ((kh*4+q) ^ (r16&7)).
//
// Row mapping: wave's A rows = mh*128 + wm*64 + i*16 + r16 (phase consumes a
// contiguous 128-row half -> staging halves align with consumption).
//
// Per K-tile t (bufA a2=t&1, bufB b3=t%3), phase = [rd-next; stage; s_barrier;
// lgkm(count); setprio1; 16 MFMA; setprio0; (vmcnt); s_barrier]:
//  P0: rd A(1,0)      ; stage A(t+1) x4 -> bufA[!a2]; lgkm(4); MFMA acc0 (A00xBk0)
//  P1: rd A(0,1)+B(k1); -                           ; lgkm(8); MFMA acc4 (A10xBk0)
//  P2: rd A(1,1)      ; stage B(t+2) c0,c1 -> b3p   ; lgkm(4); MFMA acc0 (A01xBk1)
//      vmcnt(2) [publishes ALL of tile t+1: A(t+1) issued tP0, newer = tP2's 2]
//  P3: rd A(0,0,t+1)+B(k0,t+1); stage B(t+2) c2,c3  ; lgkm(8); MFMA acc4 (A11xBk1)
//
// Hazards (all barrier-proven, no timing-based safety):
//  WAR A-stage@tP0 -> bufA[!a2]: last reads A11(t-1) issued (t-1)P2-top,
//    retired (t-1)P3-lgkm < (t-1)P3 closing bar < tP0-top.
//  WAR B-stage@tP2/P3 -> bufB[(t+2)%3]=[(t-1)%3]: last reads Bk1(t-1) issued
//    (t-1)P1-top, retired (t-1)P2-lgkm < its closing bar << tP2-top.
//  RAW t+1 reads @tP3-top: vmcnt(2)@tP2-end retires through tP0's A(t+1)
//    (and older B(t+1) from (t-1)P2/P3); barrier publishes cross-wave.
// Tail: t=NT-2: no B-stage, vmcnt(0); t=NT-1: no stage, no vm, no read-ahead,
// final lgkm(0).
// mode 1: N=3072, epilogue tanh/sigmoid -> bf16 into dst0/dst1/dst2
// mode 0: N=1024, epilogue fp32 + bias -> dstf
// ============================================================================
#define GLDS16(g, l) \
  __builtin_amdgcn_global_load_lds((const __attribute__((address_space(1))) void*)(g), \
                                   (__attribute__((address_space(3))) void*)(l), 16, 0, 0)

#define LG0 do { asm volatile("s_waitcnt lgkmcnt(0)" ::: "memory"); \
                 __builtin_amdgcn_sched_barrier(0); } while (0)
#define LG4 do { asm volatile("s_waitcnt lgkmcnt(4)" ::: "memory"); \
                 __builtin_amdgcn_sched_barrier(0); } while (0)
#define LG8 do { asm volatile("s_waitcnt lgkmcnt(8)" ::: "memory"); \
                 __builtin_amdgcn_sched_barrier(0); } while (0)
#define VMW0 asm volatile("s_waitcnt vmcnt(0)" ::: "memory")
#define VMW2 asm volatile("s_waitcnt vmcnt(2)" ::: "memory")
#define VMW4 asm volatile("s_waitcnt vmcnt(4)" ::: "memory")
#define VMNOP ((void)0)
#define BARX do { __builtin_amdgcn_s_barrier(); \
                  __builtin_amdgcn_sched_barrier(0); } while (0)

__global__ __launch_bounds__(512, 2) void gemm_act_kernel(
    const unsigned short* __restrict__ A,
    const unsigned short* __restrict__ Bt,
    const float* __restrict__ bias,
    unsigned short* __restrict__ dst0,
    unsigned short* __restrict__ dst1,
    unsigned short* __restrict__ dst2,
    float* __restrict__ dstf,
    int mode) {
  __shared__ __align__(16) unsigned short As[2][TS_];  // 64 KiB
  __shared__ __align__(16) unsigned short Bs[3][TS_];  // 96 KiB
  const int tid = threadIdx.x;
  const int lane = tid & 63;
  const int w = tid >> 6;            // wave 0..7
  const int wm = w & 1, wn = w >> 1; // 2x4 wave grid
  const int q = lane >> 4, r16 = lane & 15;
  const int tileM = blockIdx.y * 256;
  const int tileN = blockIdx.x * 256;

  // staging lane mapping (zero-conflict layout)
  const int srow = lane >> 3;                          // 0..7
  const int schunk = ((lane & 7) ^ (lane >> 3)) * 8;   // source chunk (elems)

  f32x4 zero = {0.f, 0.f, 0.f, 0.f};
  f32x4 acc[8][4];
#pragma unroll
  for (int i = 0; i < 8; ++i)
#pragma unroll
    for (int j = 0; j < 4; ++j) acc[i][j] = zero;

  // per-wave stage call c (0..3): covers 8 rows w*32 + c*8 + srow
#define STGA(tt, c, bsel) \
  GLDS16(A + (size_t)(tileM + w * 32 + (c) * 8 + srow) * K_ + (tt) * BK_ + schunk, \
         &As[bsel][(w * 32 + (c) * 8) * BK_])
#define STGB(tt, c, bsel) \
  GLDS16(Bt + (size_t)(tileN + w * 32 + (c) * 8 + srow) * K_ + (tt) * BK_ + schunk, \
         &Bs[bsel][(w * 32 + (c) * 8) * BK_])

#define RD_A(dst, mh, kh, bsel) do { \
    _Pragma("unroll") \
    for (int i = 0; i < 4; ++i) \
      dst[i] = *(const bf16x8*)&As[bsel][((mh) * 128 + wm * 64 + i * 16 + r16) * BK_ + \
                                         ((((kh) * 4 + q) ^ (r16 & 7)) * 8)]; \
  } while (0)
#define RD_B(dst, kh, bsel) do { \
    _Pragma("unroll") \
    for (int j = 0; j < 4; ++j) \
      dst[j] = *(const bf16x8*)&Bs[bsel][(wn * 64 + j * 16 + r16) * BK_ + \
                                         ((((kh) * 4 + q) ^ (r16 & 7)) * 8)]; \
  } while (0)
#define MFMA16(ib, AF, BF) do { \
    __builtin_amdgcn_s_setprio(1); \
    _Pragma("unroll") \
    for (int i = 0; i < 4; ++i) \
      _Pragma("unroll") \
      for (int j = 0; j < 4; ++j) \
        acc[(ib) + i][j] = __builtin_amdgcn_mfma_f32_16x16x32_bf16(AF[i], BF[j], acc[(ib) + i][j], 0, 0, 0); \
    __builtin_amdgcn_s_setprio(0); \
  } while (0)

#define TILE(SA, SB, VMW, P3R, LGP3) do { \
    /* P0: consume A00xBk0 (issued prev P3) */ \
    RD_A(af_b, 1, 0, a2); \
    if (SA) { STGA(t + 1, 0, a2 ^ 1); STGA(t + 1, 1, a2 ^ 1); \
              STGA(t + 1, 2, a2 ^ 1); STGA(t + 1, 3, a2 ^ 1); } \
    __builtin_amdgcn_s_barrier(); \
    LG4; \
    MFMA16(0, af_a, bfA); \
    BARX; \
    /* P1: consume A10xBk0 (issued P0) */ \
    RD_A(af_a, 0, 1, a2); \
    RD_B(bfB, 1, b3); \
    __builtin_amdgcn_s_barrier(); \
    LG8; \
    MFMA16(4, af_b, bfA); \
    BARX; \
    /* P2: consume A01xBk1 (issued P1) */ \
    RD_A(af_b, 1, 1, a2); \
    if (SB) { STGB(t + 2, 0, b3p); STGB(t + 2, 1, b3p); } \
    __builtin_amdgcn_s_barrier(); \
    LG4; \
    MFMA16(0, af_a, bfB); \
    VMW; \
    BARX; \
    /* P3: consume A11xBk1 (issued P2); read-ahead tile t+1 */ \
    if (P3R) { RD_A(af_a, 0, 0, a2 ^ 1); RD_B(bfA, 0, b3n); } \
    if (SB) { STGB(t + 2, 2, b3p); STGB(t + 2, 3, b3p); } \
    __builtin_amdgcn_s_barrier(); \
    LGP3; \
    MFMA16(4, af_b, bfB); \
    BARX; \
  } while (0)

  bf16x8 af_a[4], af_b[4], bfA[4], bfB[4];

  // prologue: B(0) x4, A(0) x4, B(1) x4 (slot-order preserved for vmcnt)
  STGB(0, 0, 0); STGB(0, 1, 0); STGB(0, 2, 0); STGB(0, 3, 0);
  STGA(0, 0, 0); STGA(0, 1, 0); STGA(0, 2, 0); STGA(0, 3, 0);
  STGB(1, 0, 1); STGB(1, 1, 1); STGB(1, 2, 1); STGB(1, 3, 1);
  VMW4;  // retire tile 0 (8 oldest), keep B(1)'s 4 in flight
  BARX;
  RD_A(af_a, 0, 0, 0);  // tile 0: A(0,0)
  RD_B(bfA, 0, 0);      // tile 0: B(k0)

  int a2 = 0, b3 = 0, b3n = 1, b3p = 2;
  int t;
#pragma unroll 1
  for (t = 0; t < NT_ - 2; ++t) {  // t = 0..13
    TILE(1, 1, VMW2, 1, LG8);
    a2 ^= 1;
    { int nb = b3n; b3n = b3p; b3p = b3; b3 = nb; }
  }
  // t = NT-2: stage A(NT-1), no B stage, drain staging with vmcnt(0)
  TILE(1, 0, VMW0, 1, LG8);
  a2 ^= 1;
  { int nb = b3n; b3n = b3p; b3p = b3; b3 = nb; }
  ++t;
  // t = NT-1: no stage, no read-ahead, final lgkm(0)
  TILE(0, 0, VMNOP, 0, LG0);

  // epilogue: C/D layout col = lane&15, row = (lane>>4)*4 + reg  [m89]
  // acc[ii][j]: rows tileM + (ii>>2)*128 + wm*64 + (ii&3)*16 + q*4 + r
  if (mode == 1) {
    int cls = tileN >> 10;  // 0: tanh->dst0, 1: sigmoid->dst1, 2: sigmoid->dst2
    unsigned short* dst = (cls == 0) ? dst0 : ((cls == 1) ? dst1 : dst2);
    int ncol0 = tileN & 1023;
#pragma unroll
    for (int ii = 0; ii < 8; ++ii) {
#pragma unroll
      for (int j = 0; j < 4; ++j) {
        int nl = wn * 64 + j * 16 + r16;
        float bb = bias[tileN + nl];
#pragma unroll
        for (int r = 0; r < 4; ++r) {
          int m = tileM + (ii >> 2) * 128 + wm * 64 + (ii & 3) * 16 + q * 4 + r;
          float u = acc[ii][j][r] + bb;
          float v = (cls == 0) ? fast_tanh(u) : fast_sigmoid(u);
          dst[(size_t)m * 1024 + (ncol0 + nl)] = f2b(v);
        }
      }
    }
  } else {
#pragma unroll
    for (int ii = 0; ii < 8; ++ii) {
#pragma unroll
      for (int j = 0; j < 4; ++j) {
        int nl = wn * 64 + j * 16 + r16;
        float bb = bias[tileN + nl];
#pragma unroll
        for (int r = 0; r < 4; ++r) {
          int m = tileM + (ii >> 2) * 128 + wm * 64 + (ii & 3) * 16 + q * 4 + r;
          dstf[(size_t)m * 1024 + tileN + nl] = acc[ii][j][r] + bb;
        }
      }
    }
  }
#undef TILE
#undef MFMA16
#undef RD_A
#undef RD_B
#undef STGA
#undef STGB
}

// ---------- scan pass A: per (b, chunk, 256-channel group) compute (prodF, localScan) ----------
__global__ void scanA_kernel(const unsigned short* __restrict__ a0,
                             const unsigned short* __restrict__ a1,
                             float* __restrict__ cF, float* __restrict__ cS) {
  int bid = blockIdx.x;
  int dhb = bid & 3;
  int j = (bid >> 2) & 63;
  int b = bid >> 8;
  int dh = dhb * 256 + threadIdx.x;
  size_t base = ((size_t)b * S_ + (size_t)j * CLEN) * DH_ + dh;
  float F = 1.f, Sv = 0.f;
#pragma unroll 4
  for (int t = 0; t < CLEN; ++t) {
    float inp = b2f(a0[base + (size_t)t * DH_]);
    float ig = b2f(a1[base + (size_t)t * DH_]);
    float f = 1.f - ig;
    F *= f;
    Sv = f * Sv + inp * ig;
  }
  int ch = b * DH_ + dh;
  cF[j * NCH + ch] = F;
  cS[j * NCH + ch] = Sv;
}

// ---------- scan pass B: sequential combine over chunks; emits carry-in per chunk + h_last ----------
__global__ void scanB_kernel(const float* __restrict__ cF, const float* __restrict__ cS,
                             float* __restrict__ cIn, float* __restrict__ hlast) {
  int ch = blockIdx.x * blockDim.x + threadIdx.x;  // 0..4095
  float h = 0.f;
#pragma unroll 4
  for (int j = 0; j < CHUNKS; ++j) {
    cIn[j * NCH + ch] = h;
    h = cF[j * NCH + ch] * h + cS[j * NCH + ch];
  }
  hlast[ch] = h;  // output 0: h[:, -1, :]
}

// ---------- scan pass C: recompute with carry-in, y = tanh(h)*og -> bf16 ----------
__global__ void scanC_kernel(const unsigned short* __restrict__ a0,
                             const unsigned short* __restrict__ a1,
                             const unsigned short* __restrict__ a2,
                             const float* __restrict__ cIn,
                             unsigned short* __restrict__ yb) {
  int bid = blockIdx.x;
  int dhb = bid & 3;
  int j = (bid >> 2) & 63;
  int b = bid >> 8;
  int dh = dhb * 256 + threadIdx.x;
  int ch = b * DH_ + dh;
  size_t base = ((size_t)b * S_ + (size_t)j * CLEN) * DH_ + dh;
  float h = cIn[j * NCH + ch];
#pragma unroll 4
  for (int t = 0; t < CLEN; ++t) {
    size_t idx = base + (size_t)t * DH_;
    float inp = b2f(a0[idx]);
    float ig = b2f(a1[idx]);
    float og = b2f(a2[idx]);
    float f = 1.f - ig;
    h = f * h + inp * ig;
    yb[idx] = f2b(fast_tanh(h) * og);
  }
}

extern "C" void kernel_launch(void* const* d_in, const int* in_sizes, int n_in,
                              void* d_out, int out_size, void* d_ws, size_t ws_size,
                              hipStream_t stream) {
  const float* x = (const float*)d_in[0];
  const float* Wp = (const float*)d_in[1];
  const float* bp = (const float*)d_in[2];
  const float* Wo = (const float*)d_in[3];
  const float* bo = (const float*)d_in[4];
  float* out = (float*)d_out;

  char* w = (char*)d_ws;
  unsigned short* xb = (unsigned short*)w;  w += (size_t)M_ * K_ * 2;       // 32 MiB
  unsigned short* wpt = (unsigned short*)w; w += (size_t)N1_ * K_ * 2;      // 6 MiB
  unsigned short* wot = (unsigned short*)w; w += (size_t)DM_ * K_ * 2;      // 2 MiB
  unsigned short* a0 = (unsigned short*)w;  w += (size_t)M_ * DH_ * 2;      // 32 MiB
  unsigned short* a1 = (unsigned short*)w;  w += (size_t)M_ * DH_ * 2;
  unsigned short* a2 = (unsigned short*)w;  w += (size_t)M_ * DH_ * 2;
  float* cF = (float*)w;  w += (size_t)NCH * CHUNKS * 4;                    // 1 MiB
  float* cS = (float*)w;  w += (size_t)NCH * CHUNKS * 4;
  float* cIn = (float*)w; w += (size_t)NCH * CHUNKS * 4;
  unsigned short* yb = xb;  // alias: xb dead after GEMM1

  cvt_x_kernel<<<(M_ * K_ / 4) / 256, 256, 0, stream>>>(x, xb);
  transpose_cvt_kernel<<<dim3(N1_ / 32, K_ / 32), 256, 0, stream>>>(Wp, wpt, K_, N1_);
  transpose_cvt_kernel<<<dim3(DM_ / 32, DH_ / 32), 256, 0, stream>>>(Wo, wot, DH_, DM_);

  gemm_act_kernel<<<dim3(N1_ / 256, M_ / 256), 512, 0, stream>>>(
      xb, wpt, bp, a0, a1, a2, nullptr, 1);

  scanA_kernel<<<B_ * CHUNKS * (DH_ / 256), 256, 0, stream>>>(a0, a1, cF, cS);
  scanB_kernel<<<NCH / 256, 256, 0, stream>>>(cF, cS, cIn, out);
  scanC_kernel<<<B_ * CHUNKS * (DH_ / 256), 256, 0, stream>>>(a0, a1, a2, cIn, yb);

  gemm_act_kernel<<<dim3(DM_ / 256, M_ / 256), 512, 0, stream>>>(
      yb, wot, bo, nullptr, nullptr, nullptr, out + 4096, 0);
}